// Round 4
// baseline (1489.605 us; speedup 1.0000x reference)
//
#include <hip/hip_runtime.h>

#define NV 500000
#define KOFF 27
#define CIN_ 32
#define COUT_ 64
#define EPS_ 1e-5f

typedef __attribute__((ext_vector_type(8))) _Float16 half8;
typedef __attribute__((ext_vector_type(4))) float floatx4;

// ws: y1h NV*64 f16 | xh NV*32 f16 | wS1 27*256 half8 | wS2 27*2*256 half8 | st 768 f32
// st: [0:128) sums1 | [128:256) sums2 | [256:384) sumsid
//     [384:512) aff1 | [512:640) aff2 | [640:768) affid

// ---- weight swizzle: wS[((k*SEG+s)*4+nf)*64 + lane] = half8 B-fragment ----
template<int CI>
__device__ __forceinline__ void fill_chunk(const float* __restrict__ w,
                                           half8* __restrict__ wS, int t) {
  constexpr int SEG = CI / 32;
  int k = t / (SEG * 256);
  int r = t - k * SEG * 256;
  int s = r >> 8;
  int nf = (r >> 6) & 3;
  int lane = r & 63;
  int m = lane & 15, quad = lane >> 4;
  int co = nf * 16 + m;
  int ci0 = s * 32 + quad * 8;
  half8 h;
#pragma unroll
  for (int j = 0; j < 8; ++j)
    h[j] = (_Float16)w[(size_t)(k * CI + ci0 + j) * COUT_ + co];
  wS[t] = h;
}

__global__ __launch_bounds__(256) void prep_weights(
    const float* __restrict__ w1, const float* __restrict__ w2,
    _Float16* __restrict__ wS1, _Float16* __restrict__ wS2,
    float* __restrict__ st) {
  int t = blockIdx.x * 256 + threadIdx.x;
  if (t < 768) st[t] = 0.f;
  const int T1 = KOFF * 256;       // CI=32 chunks
  const int T2 = KOFF * 2 * 256;   // CI=64 chunks
  if (t < T1) fill_chunk<32>(w1, (half8*)wS1, t);
  else if (t < T1 + T2) fill_chunk<64>(w2, (half8*)wS2, t - T1);
}

// ---- prep x: cast to f16 + ident-branch stats (x read once, wave-uniform) ----
__global__ __launch_bounds__(256) void prep_x(
    const float* __restrict__ x, _Float16* __restrict__ xh,
    const float* __restrict__ wid, float* __restrict__ st) {
  int tid = threadIdx.x, lane = tid & 63;
  int wv = blockIdx.x * 4 + (tid >> 6);
  int nw = gridDim.x * 4;
  float wcol[CIN_];
#pragma unroll
  for (int ci = 0; ci < CIN_; ++ci) wcol[ci] = wid[ci * COUT_ + lane];
  half8* xh8 = (half8*)xh;
  float s = 0.f, ss = 0.f;
  for (int v = wv; v < NV; v += nw) {
    const float* xr = x + (size_t)v * CIN_;
    float xv[CIN_];
#pragma unroll
    for (int ci = 0; ci < CIN_; ++ci) xv[ci] = xr[ci];
    float d = 0.f;
#pragma unroll
    for (int ci = 0; ci < CIN_; ++ci) d = fmaf(xv[ci], wcol[ci], d);
    if (lane < 4) {
      half8 h;
#pragma unroll
      for (int j = 0; j < 8; ++j) h[j] = (_Float16)xv[lane * 8 + j];
      xh8[(size_t)v * 4 + lane] = h;
    }
    s += d;
    ss = fmaf(d, d, ss);
  }
  __shared__ float ls[128];
  if (tid < 128) ls[tid] = 0.f;
  __syncthreads();
  atomicAdd(&ls[lane], s);
  atomicAdd(&ls[64 + lane], ss);
  __syncthreads();
  if (tid < 128) atomicAdd(&st[256 + tid], ls[tid]);
}

// ---- conv v4: conflict-free LDS B + register gather ring + fused stats ----

template<int SEG>
__device__ __forceinline__ void stageW(const half8* __restrict__ wS,
                                       half8* __restrict__ lds,
                                       int k0, int kp, int tid) {
  __syncthreads();
  int chunks = kp * SEG * 256;
  const half8* src = wS + k0 * SEG * 256;
  for (int i = tid; i < chunks; i += 1024) lds[i] = src[i];
  __syncthreads();
}

template<int CI, int KPC, int D>
__device__ __forceinline__ void run_phase(
    const half8* __restrict__ fp, const int* __restrict__ nbr,
    const half8* __restrict__ lds, int k0,
    int v0, int v1, int lane, floatx4 acc[2][4]) {
  constexpr int SEG = CI / 32;
  constexpr int ROWH8 = CI / 8;
  int quad = lane >> 4;

  int j0[KPC], j1[KPC];
#pragma unroll
  for (int k = 0; k < KPC; ++k) {
    j0[k] = nbr[(k0 + k) * NV + v0] * ROWH8;
    j1[k] = nbr[(k0 + k) * NV + v1] * ROWH8;
  }

  half8 ring[D][2][SEG];
#pragma unroll
  for (int p = 0; p < D; ++p)
#pragma unroll
    for (int s = 0; s < SEG; ++s) {
      ring[p][0][s] = fp[(size_t)j0[p] + s * 4 + quad];
      ring[p][1][s] = fp[(size_t)j1[p] + s * 4 + quad];
    }

#pragma unroll
  for (int k = 0; k < KPC; ++k) {
#pragma unroll
    for (int s = 0; s < SEG; ++s) {
#pragma unroll
      for (int nf = 0; nf < 4; ++nf) {
        half8 bf = lds[((k * SEG + s) * 4 + nf) * 64 + lane];
        acc[0][nf] = __builtin_amdgcn_mfma_f32_16x16x32_f16(ring[k % D][0][s], bf, acc[0][nf], 0, 0, 0);
        acc[1][nf] = __builtin_amdgcn_mfma_f32_16x16x32_f16(ring[k % D][1][s], bf, acc[1][nf], 0, 0, 0);
      }
    }
    if (k + D < KPC) {
#pragma unroll
      for (int s = 0; s < SEG; ++s) {
        ring[k % D][0][s] = fp[(size_t)j0[k + D] + s * 4 + quad];
        ring[k % D][1][s] = fp[(size_t)j1[k + D] + s * 4 + quad];
      }
    }
  }
}

template<int CI, bool WF16>
__global__ __launch_bounds__(1024, 4) void conv_mfma_v4(
    const _Float16* __restrict__ feats, const int* __restrict__ nbr,
    const _Float16* __restrict__ wS, float* __restrict__ outF,
    _Float16* __restrict__ outH, float* __restrict__ stats) {
  constexpr int SEG = CI / 32;
  constexpr int LDSH8 = (CI == 64) ? 7 * 2 * 256 : 9 * 256;
  __shared__ half8 ldsB[LDSH8];

  int tid = threadIdx.x;
  int wave = tid >> 6, lane = tid & 63;
  int m = lane & 15, quad = lane >> 4;
  int vbase = (blockIdx.x * 16 + wave) * 32;
  int v0 = vbase + m;
  int v1 = vbase + 16 + m;
  v0 = v0 < NV ? v0 : NV - 1;
  v1 = v1 < NV ? v1 : NV - 1;
  const half8* fp = (const half8*)feats;
  const half8* wp = (const half8*)wS;

  floatx4 acc[2][4];
#pragma unroll
  for (int g = 0; g < 2; ++g)
#pragma unroll
    for (int nf = 0; nf < 4; ++nf) acc[g][nf] = (floatx4){0.f, 0.f, 0.f, 0.f};

  if constexpr (CI == 64) {
    stageW<SEG>(wp, ldsB, 0, 7, tid);
    run_phase<CI, 7, 3>(fp, nbr, ldsB, 0, v0, v1, lane, acc);
    stageW<SEG>(wp, ldsB, 7, 7, tid);
    run_phase<CI, 7, 3>(fp, nbr, ldsB, 7, v0, v1, lane, acc);
    stageW<SEG>(wp, ldsB, 14, 7, tid);
    run_phase<CI, 7, 3>(fp, nbr, ldsB, 14, v0, v1, lane, acc);
    stageW<SEG>(wp, ldsB, 21, 6, tid);
    run_phase<CI, 6, 3>(fp, nbr, ldsB, 21, v0, v1, lane, acc);
  } else {
    stageW<SEG>(wp, ldsB, 0, 9, tid);
    run_phase<CI, 9, 4>(fp, nbr, ldsB, 0, v0, v1, lane, acc);
    stageW<SEG>(wp, ldsB, 9, 9, tid);
    run_phase<CI, 9, 4>(fp, nbr, ldsB, 9, v0, v1, lane, acc);
    stageW<SEG>(wp, ldsB, 18, 9, tid);
    run_phase<CI, 9, 4>(fp, nbr, ldsB, 18, v0, v1, lane, acc);
  }

  // epilogue: store + fused per-channel stats (sum, sumsq)
  __syncthreads();
  float* ls = (float*)ldsB;
  if (tid < 128) ls[tid] = 0.f;
  __syncthreads();
#pragma unroll
  for (int nf = 0; nf < 4; ++nf) {
    float s = 0.f, ss = 0.f;
#pragma unroll
    for (int g = 0; g < 2; ++g)
#pragma unroll
      for (int r = 0; r < 4; ++r) {
        int row = vbase + g * 16 + quad * 4 + r;
        if (row < NV) {
          float v = acc[g][nf][r];
          size_t o = (size_t)row * COUT_ + nf * 16 + m;
          if (WF16) outH[o] = (_Float16)v;
          else outF[o] = v;
          s += v;
          ss = fmaf(v, v, ss);
        }
      }
    s += __shfl_xor(s, 16, 64);
    s += __shfl_xor(s, 32, 64);
    ss += __shfl_xor(ss, 16, 64);
    ss += __shfl_xor(ss, 32, 64);
    if (quad == 0) {
      atomicAdd(&ls[nf * 16 + m], s);
      atomicAdd(&ls[64 + nf * 16 + m], ss);
    }
  }
  __syncthreads();
  if (tid < 128) atomicAdd(&stats[tid], ls[tid]);
}

// ---- BN finalize ----
__global__ void finalize12(float* __restrict__ st,
                           const float* __restrict__ g1, const float* __restrict__ b1,
                           const float* __restrict__ gid, const float* __restrict__ bid) {
  int t = threadIdx.x;  // 128
  int c = t & 63;
  const float* sums = (t < 64) ? st : st + 256;
  const float* g = (t < 64) ? g1 : gid;
  const float* b = (t < 64) ? b1 : bid;
  float* o = (t < 64) ? st + 384 : st + 640;
  float m = sums[c] * (1.0f / NV);
  float var = sums[64 + c] * (1.0f / NV) - m * m;
  float sc = g[c] / sqrtf(var + EPS_);
  o[c] = sc;
  o[64 + c] = b[c] - m * sc;
}

__global__ void finalize_kernel(const float* __restrict__ sums,
                                const float* __restrict__ g,
                                const float* __restrict__ b,
                                float* __restrict__ out) {
  int c = threadIdx.x;
  float m = sums[c] * (1.0f / NV);
  float var = sums[64 + c] * (1.0f / NV) - m * m;
  float sc = g[c] / sqrtf(var + EPS_);
  out[c] = sc;
  out[64 + c] = b[c] - m * sc;
}

__global__ __launch_bounds__(256) void bnrelu_f16_kernel(
    _Float16* __restrict__ y, const float* __restrict__ scsh) {
  size_t q = (size_t)blockIdx.x * 256 + threadIdx.x;
  if (q >= (size_t)NV * COUT_ / 8) return;
  int c0 = (int)(q & 7) * 8;
  half8 v = ((const half8*)y)[q];
#pragma unroll
  for (int jj = 0; jj < 8; ++jj) {
    float f = fmaxf(fmaf((float)v[jj], scsh[c0 + jj], scsh[64 + c0 + jj]), 0.f);
    v[jj] = (_Float16)f;
  }
  ((half8*)y)[q] = v;
}

// out = relu(bn2(y2) + bnid(x@wid)), y2 = d_out in-place
__global__ __launch_bounds__(256) void final_kernel(
    const float* __restrict__ x, const float* __restrict__ wid,
    float* __restrict__ y2out, const float* __restrict__ ss2,
    const float* __restrict__ ssid) {
  int lane = threadIdx.x & 63;
  int wv = blockIdx.x * 4 + (threadIdx.x >> 6);
  int nw = gridDim.x * 4;
  float wcol[CIN_];
#pragma unroll
  for (int ci = 0; ci < CIN_; ++ci) wcol[ci] = wid[ci * COUT_ + lane];
  float sc2 = ss2[lane], sh2 = ss2[64 + lane];
  float sci = ssid[lane], shi = ssid[64 + lane];
  for (int v = wv; v < NV; v += nw) {
    const float* xr = x + (size_t)v * CIN_;
    float d = 0.f;
#pragma unroll
    for (int ci = 0; ci < CIN_; ++ci) d = fmaf(xr[ci], wcol[ci], d);
    size_t o = (size_t)v * COUT_ + lane;
    float r = fmaf(y2out[o], sc2, sh2) + fmaf(d, sci, shi);
    y2out[o] = fmaxf(r, 0.f);
  }
}

extern "C" void kernel_launch(void* const* d_in, const int* in_sizes, int n_in,
                              void* d_out, int out_size, void* d_ws, size_t ws_size,
                              hipStream_t stream) {
  const float* x   = (const float*)d_in[0];
  const int*   nbr = (const int*)d_in[1];
  const float* w1  = (const float*)d_in[2];
  const float* g1  = (const float*)d_in[3];
  const float* b1  = (const float*)d_in[4];
  const float* w2  = (const float*)d_in[5];
  const float* g2  = (const float*)d_in[6];
  const float* b2  = (const float*)d_in[7];
  const float* wid = (const float*)d_in[8];
  const float* gid = (const float*)d_in[9];
  const float* bid = (const float*)d_in[10];
  float* out = (float*)d_out;

  _Float16* y1h = (_Float16*)d_ws;                     // NV*64
  _Float16* xh  = y1h + (size_t)NV * COUT_;            // NV*32
  _Float16* wS1 = xh + (size_t)NV * CIN_;              // 27*256*8
  _Float16* wS2 = wS1 + (size_t)KOFF * 256 * 8;        // 27*2*256*8
  float*    st  = (float*)(wS2 + (size_t)KOFF * 2 * 256 * 8);

  const int NWG = (NV + 511) / 512;  // 977

  prep_weights<<<81, 256, 0, stream>>>(w1, w2, wS1, wS2, st);
  prep_x<<<512, 256, 0, stream>>>(x, xh, wid, st);
  conv_mfma_v4<CIN_, true><<<NWG, 1024, 0, stream>>>(xh, nbr, wS1, nullptr, y1h, st + 0);
  finalize12<<<1, 128, 0, stream>>>(st, g1, b1, gid, bid);
  bnrelu_f16_kernel<<<(NV * COUT_ / 8 + 255) / 256, 256, 0, stream>>>(y1h, st + 384);
  conv_mfma_v4<COUT_, false><<<NWG, 1024, 0, stream>>>(y1h, nbr, wS2, out, nullptr, st + 128);
  finalize_kernel<<<1, 64, 0, stream>>>(st + 128, g2, b2, st + 512);
  final_kernel<<<4096, 256, 0, stream>>>(x, wid, out, st + 512, st + 640);
}